// Round 4
// baseline (923.892 us; speedup 1.0000x reference)
//
#include <hip/hip_runtime.h>
#include <hip/hip_bf16.h>

// Problem constants
// B=2, M=384, N=96, D=512, J=640, C=1024
// a = enc @ w_audio + b_audio : [768][640]   (proj_kernel, MFMA bf16-split)
// t = dec @ w_text  + b_text  : [192][640]
// out[r][c] = sum_j tanh(a[..][j] + t[..][j]) * w_join[j][c] + b_join[c]
//   r = (b*384+m)*96 + n  (73728 rows), c in [0,1024)

typedef float f32x4 __attribute__((ext_vector_type(4)));
typedef short short8 __attribute__((ext_vector_type(8)));

// Static device scratch — fully rewritten every launch (graph-replay safe).
__device__ float g_A[768 * 640];
__device__ float g_T[192 * 640];
__device__ short g_W2[80 * 1024 * 8];        // w_join bf16, [g][c][8k]
__device__ short g_Xph[960 * 512];           // enc(768)+dec(192) bf16 hi, fragment layout
__device__ short g_Xpl[960 * 512];           // residual lo
__device__ short g_Wph[2 * 64 * 640 * 8];    // w_audio/w_text bf16 hi, [mat][g][j][8k]
__device__ short g_Wpl[2 * 64 * 640 * 8];    // residual lo

__device__ __forceinline__ unsigned short f2bf(float f) {
    unsigned u = __float_as_uint(f);
    unsigned r = u + 0x7fffu + ((u >> 16) & 1u);   // RNE
    return (unsigned short)(r >> 16);
}
__device__ __forceinline__ float bf2f(unsigned short h) {
    return __uint_as_float((unsigned)h << 16);
}
__device__ __forceinline__ float fast_tanh(float x) {
    x = fminf(fmaxf(x, -10.f), 10.f);
    float e2 = __expf(x * 2.0f);
    return 1.f - 2.f / (e2 + 1.f);
}

// ---------------------------------------------------------------------------
// Pack kernel: 880 blocks x 256 = 225280 threads.
//   [0, 61440)        : X = enc|dec -> bf16 hi/lo fragments [row/16][g][row%16][8]
//   [61440, 143360)   : W = w_audio|w_text -> hi/lo [mat*64+g][j][8]  (k-group layout)
//   [143360, 225280)  : w_join -> g_W2 [g][c][8]  (bf16, single)
// ---------------------------------------------------------------------------
__global__ __launch_bounds__(256) void pack_kernel(
    const float* __restrict__ enc, const float* __restrict__ dec,
    const float* __restrict__ w_audio, const float* __restrict__ w_text,
    const float* __restrict__ w_join)
{
    int idx = blockIdx.x * 256 + threadIdx.x;
    if (idx < 61440) {
        int row = idx >> 6, g = idx & 63;
        const float* src = (row < 768) ? (enc + (size_t)row * 512)
                                       : (dec + (size_t)(row - 768) * 512);
        short8 hi, lo;
        #pragma unroll
        for (int i = 0; i < 8; ++i) {
            float x = src[g * 8 + i];
            unsigned short h = f2bf(x);
            hi[i] = (short)h;
            lo[i] = (short)f2bf(x - bf2f(h));
        }
        size_t off = ((size_t)(row >> 4) * 64 + g) * 16 + (row & 15);
        ((short8*)g_Xph)[off] = hi;
        ((short8*)g_Xpl)[off] = lo;
    } else if (idx < 143360) {
        int e = idx - 61440;
        int mat = e / 40960; e -= mat * 40960;
        int g = e / 640, j = e - g * 640;
        const float* W = mat ? w_text : w_audio;
        short8 hi, lo;
        #pragma unroll
        for (int i = 0; i < 8; ++i) {
            float x = W[(size_t)(g * 8 + i) * 640 + j];
            unsigned short h = f2bf(x);
            hi[i] = (short)h;
            lo[i] = (short)f2bf(x - bf2f(h));
        }
        size_t off = (size_t)(mat * 64 + g) * 640 + j;
        ((short8*)g_Wph)[off] = hi;
        ((short8*)g_Wpl)[off] = lo;
    } else {
        int e = idx - 143360;                 // 0..81919
        int g = e >> 10, c = e & 1023;
        short8 v;
        #pragma unroll
        for (int j = 0; j < 8; ++j)
            v[j] = (short)f2bf(w_join[(size_t)(g * 8 + j) * 1024 + c]);
        ((short8*)g_W2)[e] = v;
    }
}

// ---------------------------------------------------------------------------
// Projection GEMM via MFMA bf16 hi/lo split (fp32-equivalent accuracy):
//   x*w ~= xh*wh + xl*wh + xh*wl   (lo*lo ~ 2^-18, dropped)
// 30 blocks (15 M-tiles x 2 col-halves) x 256 threads; all operands from L2.
// Output: g_A rows 0..767 (enc@w_audio+b_audio), g_T rows 0..191.
// ---------------------------------------------------------------------------
__global__ __launch_bounds__(256) void proj_kernel(
    const float* __restrict__ b_audio, const float* __restrict__ b_text)
{
    const int bid = blockIdx.x;            // 0..29
    const int mtile = bid >> 1, nhalf = bid & 1;
    const int tid  = threadIdx.x;
    const int lane = tid & 63, wave = tid >> 6, l15 = lane & 15, quad = lane >> 4;
    const int mat  = (mtile >= 12) ? 1 : 0;       // 12*64 = 768 = enc rows
    const int colw = nhalf * 320 + wave * 80;     // 5 nt-tiles of 16
    const float* bias = mat ? b_text : b_audio;
    float* O = mat ? g_T : g_A;
    const int orow0 = mtile * 64 - mat * 768;

    const short8* Xh = (const short8*)g_Xph;
    const short8* Xl = (const short8*)g_Xpl;
    const short8* Wh = (const short8*)g_Wph;
    const short8* Wl = (const short8*)g_Wpl;

    f32x4 acc[4][5] = {};
    for (int kb = 0; kb < 512; kb += 32) {
        const int g = (kb >> 3) + quad;           // k-group 0..63
        short8 ah[4], al[4], bh[5], bl[5];
        #pragma unroll
        for (int mt = 0; mt < 4; ++mt) {
            size_t xo = ((size_t)(mtile * 4 + mt) * 64 + g) * 16 + l15;
            ah[mt] = Xh[xo]; al[mt] = Xl[xo];
        }
        #pragma unroll
        for (int nt = 0; nt < 5; ++nt) {
            size_t wo = (size_t)(mat * 64 + g) * 640 + colw + nt * 16 + l15;
            bh[nt] = Wh[wo]; bl[nt] = Wl[wo];
        }
        #pragma unroll
        for (int mt = 0; mt < 4; ++mt)
            #pragma unroll
            for (int nt = 0; nt < 5; ++nt) {
                acc[mt][nt] = __builtin_amdgcn_mfma_f32_16x16x32_bf16(bh[nt], ah[mt], acc[mt][nt], 0, 0, 0);
                acc[mt][nt] = __builtin_amdgcn_mfma_f32_16x16x32_bf16(bh[nt], al[mt], acc[mt][nt], 0, 0, 0);
                acc[mt][nt] = __builtin_amdgcn_mfma_f32_16x16x32_bf16(bl[nt], ah[mt], acc[mt][nt], 0, 0, 0);
            }
    }
    // lane l, reg rg -> out[row = mt*16 + (l&15)][col = colw + nt*16 + (l>>4)*4 + rg]
    #pragma unroll
    for (int nt = 0; nt < 5; ++nt) {
        const int c4 = colw + nt * 16 + quad * 4;
        f32x4 bj = *(const f32x4*)(bias + c4);
        #pragma unroll
        for (int mt = 0; mt < 4; ++mt) {
            f32x4 v = acc[mt][nt] + bj;
            *(f32x4*)(O + (size_t)(orow0 + mt * 16 + l15) * 640 + c4) = v;
        }
    }
}

// ---------------------------------------------------------------------------
// Main fused join kernel: 1152 blocks x 256 threads (4 waves).
// v4: v2 geometry (64-row tile, 80 KiB LDS, 2 blocks/CU) — the proven
//     FETCH=9MB / WRITE=388MB operating point. v3's 4-blocks/CU doubled
//     in-flight NT store streams and thrashed L2 (read-allocate on partial
//     lines, FETCH 600MB). New: 3-buffer software-pipelined fragment
//     prefetch (2 load batches in flight, fully unrolled -> static register
//     rotation) + s_setprio around MFMA clusters (waves independent, no
//     barriers in K-loop).
// ---------------------------------------------------------------------------
__global__ __launch_bounds__(256, 2) void join_kernel(
    const float* __restrict__ b_join, // [1024]
    float* __restrict__ out)          // [73728][1024]
{
    __shared__ char hb[64 * 1280];    // 80 KiB: row stride 1280B, 16B groups XOR-swizzled
    const int tid = threadIdx.x;
    const int r0  = blockIdx.x * 64;

    // ---- Phase 1: h = tanh(a + t) -> LDS (bf16), once per element ----
    for (int e = tid; e < 64 * 160; e += 256) {
        int row = e / 160;
        int q   = e - row * 160;       // float4 index within row, j = 4q
        int r   = r0 + row;
        int arow = r / 96;                              // b*384 + m
        int trow = (r / 36864) * 96 + (r - arow * 96);  // b*96 + n
        int j = q * 4;
        f32x4 av = *(const f32x4*)(g_A + arow * 640 + j);
        f32x4 tv = *(const f32x4*)(g_T + trow * 640 + j);
        float h0 = fast_tanh(av[0] + tv[0]);
        float h1 = fast_tanh(av[1] + tv[1]);
        float h2 = fast_tanh(av[2] + tv[2]);
        float h3 = fast_tanh(av[3] + tv[3]);
        unsigned lo = (unsigned)f2bf(h0) | ((unsigned)f2bf(h1) << 16);
        unsigned hi = (unsigned)f2bf(h2) | ((unsigned)f2bf(h3) << 16);
        // group g = j/8 = q/2, swizzle g ^= (row&7); half-group select = q&1
        unsigned off = row * 1280 + (((unsigned)((q >> 1) ^ (row & 7))) << 4) + (q & 1) * 8;
        *(uint2*)(hb + off) = make_uint2(lo, hi);
    }
    __syncthreads();

    // ---- Phase 2: MFMA GEMM, 3-buffer pipelined fragments, no barriers ----
    const int lane = tid & 63;
    const int wave = tid >> 6;     // 0..3
    const int l15  = lane & 15;
    const int quad = lane >> 4;    // 0..3

    for (int ct = 0; ct < 4; ++ct) {
        const int colw = ct * 256 + wave * 64;
        f32x4 acc[4][4] = {};
        short8 af[3][4], bw[3][4];

        auto ld = [&](int buf, int s) {
            const int g = s * 4 + quad;            // 16B-group index along K
            #pragma unroll
            for (int mt = 0; mt < 4; ++mt) {
                int rw = mt * 16 + l15;
                af[buf][mt] = *(const short8*)(hb + rw * 1280 + ((unsigned)(g ^ (rw & 7)) << 4));
            }
            #pragma unroll
            for (int nt = 0; nt < 4; ++nt)
                bw[buf][nt] = *(const short8*)(g_W2 + ((size_t)g * 1024 + colw + nt * 16 + l15) * 8);
        };

        ld(0, 0);
        ld(1, 1);
        #pragma unroll
        for (int s = 0; s < 20; ++s) {
            const int cur = s % 3;
            if (s + 2 < 20) ld((s + 2) % 3, s + 2);   // 2 batches in flight
            __builtin_amdgcn_s_setprio(1);
            #pragma unroll
            for (int mt = 0; mt < 4; ++mt)
                #pragma unroll
                for (int nt = 0; nt < 4; ++nt)
                    acc[mt][nt] = __builtin_amdgcn_mfma_f32_16x16x32_bf16(
                        bw[cur][nt], af[cur][mt], acc[mt][nt], 0, 0, 0);
            __builtin_amdgcn_s_setprio(0);
        }

        // epilogue: add b_join, float4 non-temporal stores (exact v2 pattern:
        // mt-outer/nt-inner so both 64B halves of each 128B line are adjacent).
        f32x4 bj[4];
        #pragma unroll
        for (int nt = 0; nt < 4; ++nt)
            bj[nt] = *(const f32x4*)(b_join + colw + nt * 16 + quad * 4);
        #pragma unroll
        for (int mt = 0; mt < 4; ++mt) {
            float* orow = out + (size_t)(r0 + mt * 16 + l15) * 1024;
            #pragma unroll
            for (int nt = 0; nt < 4; ++nt) {
                int c4 = colw + nt * 16 + quad * 4;
                f32x4 v = acc[mt][nt] + bj[nt];
                __builtin_nontemporal_store(v, (f32x4*)(orow + c4));
            }
        }
    }
}

// ---------------------------------------------------------------------------
extern "C" void kernel_launch(void* const* d_in, const int* in_sizes, int n_in,
                              void* d_out, int out_size, void* d_ws, size_t ws_size,
                              hipStream_t stream) {
    const float* enc     = (const float*)d_in[0];
    const float* dec     = (const float*)d_in[1];
    const float* w_audio = (const float*)d_in[2];
    const float* b_audio = (const float*)d_in[3];
    const float* w_text  = (const float*)d_in[4];
    const float* b_text  = (const float*)d_in[5];
    const float* w_join  = (const float*)d_in[6];
    const float* b_join  = (const float*)d_in[7];
    float* out = (float*)d_out;

    pack_kernel<<<dim3(880), dim3(256), 0, stream>>>(enc, dec, w_audio, w_text, w_join);
    proj_kernel<<<dim3(30), dim3(256), 0, stream>>>(b_audio, b_text);
    join_kernel<<<dim3(1152), dim3(256), 0, stream>>>(b_join, out);
}

// Round 5
// 498.355 us; speedup vs baseline: 1.8539x; 1.8539x over previous
//
#include <hip/hip_runtime.h>
#include <hip/hip_bf16.h>

// Problem constants
// B=2, M=384, N=96, D=512, J=640, C=1024
// a = enc @ w_audio + b_audio : [768][640]   (proj_kernel, MFMA bf16-split)
// t = dec @ w_text  + b_text  : [192][640]
// out[r][c] = sum_j tanh(a[..][j] + t[..][j]) * w_join[j][c] + b_join[c]
//   r = (b*384+m)*96 + n  (73728 rows), c in [0,1024)

typedef float f32x4 __attribute__((ext_vector_type(4)));
typedef short short8 __attribute__((ext_vector_type(8)));

// Static device scratch — fully rewritten every launch (graph-replay safe).
__device__ float g_A[768 * 640];
__device__ float g_T[192 * 640];
__device__ short g_W2[80 * 1024 * 8];        // w_join bf16, [g][c][8k]
__device__ short g_Xph[960 * 512];           // enc(768)+dec(192) bf16 hi, fragment layout
__device__ short g_Xpl[960 * 512];           // residual lo
__device__ short g_Wph[2 * 64 * 640 * 8];    // w_audio/w_text bf16 hi, [mat][g][j][8k]
__device__ short g_Wpl[2 * 64 * 640 * 8];    // residual lo

__device__ __forceinline__ unsigned short f2bf(float f) {
    unsigned u = __float_as_uint(f);
    unsigned r = u + 0x7fffu + ((u >> 16) & 1u);   // RNE
    return (unsigned short)(r >> 16);
}
__device__ __forceinline__ float bf2f(unsigned short h) {
    return __uint_as_float((unsigned)h << 16);
}
__device__ __forceinline__ float fast_tanh(float x) {
    x = fminf(fmaxf(x, -10.f), 10.f);
    float e2 = __expf(x * 2.0f);
    return 1.f - 2.f / (e2 + 1.f);
}

// ---------------------------------------------------------------------------
// Pack kernel: 880 blocks x 256 = 225280 threads.
//   [0, 61440)        : X = enc|dec -> bf16 hi/lo fragments [row/16][g][row%16][8]
//   [61440, 143360)   : W = w_audio|w_text -> hi/lo [mat*64+g][j][8]  (k-group layout)
//   [143360, 225280)  : w_join -> g_W2 [g][c][8]  (bf16, single)
// ---------------------------------------------------------------------------
__global__ __launch_bounds__(256) void pack_kernel(
    const float* __restrict__ enc, const float* __restrict__ dec,
    const float* __restrict__ w_audio, const float* __restrict__ w_text,
    const float* __restrict__ w_join)
{
    int idx = blockIdx.x * 256 + threadIdx.x;
    if (idx < 61440) {
        int row = idx >> 6, g = idx & 63;
        const float* src = (row < 768) ? (enc + (size_t)row * 512)
                                       : (dec + (size_t)(row - 768) * 512);
        short8 hi, lo;
        #pragma unroll
        for (int i = 0; i < 8; ++i) {
            float x = src[g * 8 + i];
            unsigned short h = f2bf(x);
            hi[i] = (short)h;
            lo[i] = (short)f2bf(x - bf2f(h));
        }
        size_t off = ((size_t)(row >> 4) * 64 + g) * 16 + (row & 15);
        ((short8*)g_Xph)[off] = hi;
        ((short8*)g_Xpl)[off] = lo;
    } else if (idx < 143360) {
        int e = idx - 61440;
        int mat = e / 40960; e -= mat * 40960;
        int g = e / 640, j = e - g * 640;
        const float* W = mat ? w_text : w_audio;
        short8 hi, lo;
        #pragma unroll
        for (int i = 0; i < 8; ++i) {
            float x = W[(size_t)(g * 8 + i) * 640 + j];
            unsigned short h = f2bf(x);
            hi[i] = (short)h;
            lo[i] = (short)f2bf(x - bf2f(h));
        }
        size_t off = (size_t)(mat * 64 + g) * 640 + j;
        ((short8*)g_Wph)[off] = hi;
        ((short8*)g_Wpl)[off] = lo;
    } else {
        int e = idx - 143360;                 // 0..81919
        int g = e >> 10, c = e & 1023;
        short8 v;
        #pragma unroll
        for (int j = 0; j < 8; ++j)
            v[j] = (short)f2bf(w_join[(size_t)(g * 8 + j) * 1024 + c]);
        ((short8*)g_W2)[e] = v;
    }
}

// ---------------------------------------------------------------------------
// Projection GEMM via MFMA bf16 hi/lo split (fp32-equivalent accuracy):
//   x*w ~= xh*wh + xl*wh + xh*wl   (lo*lo ~ 2^-18, dropped)
// 30 blocks (15 M-tiles x 2 col-halves) x 256 threads; all operands from L2.
// Output: g_A rows 0..767 (enc@w_audio+b_audio), g_T rows 0..191.
// ---------------------------------------------------------------------------
__global__ __launch_bounds__(256) void proj_kernel(
    const float* __restrict__ b_audio, const float* __restrict__ b_text)
{
    const int bid = blockIdx.x;            // 0..29
    const int mtile = bid >> 1, nhalf = bid & 1;
    const int tid  = threadIdx.x;
    const int lane = tid & 63, wave = tid >> 6, l15 = lane & 15, quad = lane >> 4;
    const int mat  = (mtile >= 12) ? 1 : 0;       // 12*64 = 768 = enc rows
    const int colw = nhalf * 320 + wave * 80;     // 5 nt-tiles of 16
    const float* bias = mat ? b_text : b_audio;
    float* O = mat ? g_T : g_A;
    const int orow0 = mtile * 64 - mat * 768;

    const short8* Xh = (const short8*)g_Xph;
    const short8* Xl = (const short8*)g_Xpl;
    const short8* Wh = (const short8*)g_Wph;
    const short8* Wl = (const short8*)g_Wpl;

    f32x4 acc[4][5] = {};
    for (int kb = 0; kb < 512; kb += 32) {
        const int g = (kb >> 3) + quad;           // k-group 0..63
        short8 ah[4], al[4], bh[5], bl[5];
        #pragma unroll
        for (int mt = 0; mt < 4; ++mt) {
            size_t xo = ((size_t)(mtile * 4 + mt) * 64 + g) * 16 + l15;
            ah[mt] = Xh[xo]; al[mt] = Xl[xo];
        }
        #pragma unroll
        for (int nt = 0; nt < 5; ++nt) {
            size_t wo = (size_t)(mat * 64 + g) * 640 + colw + nt * 16 + l15;
            bh[nt] = Wh[wo]; bl[nt] = Wl[wo];
        }
        #pragma unroll
        for (int mt = 0; mt < 4; ++mt)
            #pragma unroll
            for (int nt = 0; nt < 5; ++nt) {
                acc[mt][nt] = __builtin_amdgcn_mfma_f32_16x16x32_bf16(bh[nt], ah[mt], acc[mt][nt], 0, 0, 0);
                acc[mt][nt] = __builtin_amdgcn_mfma_f32_16x16x32_bf16(bh[nt], al[mt], acc[mt][nt], 0, 0, 0);
                acc[mt][nt] = __builtin_amdgcn_mfma_f32_16x16x32_bf16(bl[nt], ah[mt], acc[mt][nt], 0, 0, 0);
            }
    }
    // lane l, reg rg -> out[row = mt*16 + (l&15)][col = colw + nt*16 + (l>>4)*4 + rg]
    #pragma unroll
    for (int nt = 0; nt < 5; ++nt) {
        const int c4 = colw + nt * 16 + quad * 4;
        f32x4 bj = *(const f32x4*)(bias + c4);
        #pragma unroll
        for (int mt = 0; mt < 4; ++mt) {
            f32x4 v = acc[mt][nt] + bj;
            *(f32x4*)(O + (size_t)(orow0 + mt * 16 + l15) * 640 + c4) = v;
        }
    }
}

// ---------------------------------------------------------------------------
// Main fused join kernel: 1152 blocks x 256 threads (4 waves).
// v5: EXACT v2 structure (the proven 228us / FETCH=9MB operating point:
//     64-row tile, 80KiB LDS, 2 blocks/CU, compiler-scheduled K-loop, NO
//     setprio, NO manual pipeline — v3/v4 showed any scheduling perturbation
//     collapses the memory system). Single change vs v2: PLAIN stores
//     instead of nontemporal. v2's NT path throttled writes at ~1.7TB/s;
//     the epilogue writes complete 64B sectors per instruction and both
//     halves of each 128B line back-to-back, so normal write-back should
//     stream at >=3TB/s without read-allocate (v0's RFO came from 4B
//     scalar stores, not from caching policy).
// ---------------------------------------------------------------------------
__global__ __launch_bounds__(256, 2) void join_kernel(
    const float* __restrict__ b_join, // [1024]
    float* __restrict__ out)          // [73728][1024]
{
    __shared__ char hb[64 * 1280];    // 80 KiB: row stride 1280B, 16B groups XOR-swizzled
    const int tid = threadIdx.x;
    const int r0  = blockIdx.x * 64;

    // ---- Phase 1: h = tanh(a + t) -> LDS (bf16), once per element ----
    for (int e = tid; e < 64 * 160; e += 256) {
        int row = e / 160;
        int q   = e - row * 160;       // float4 index within row, j = 4q
        int r   = r0 + row;
        int arow = r / 96;                              // b*384 + m
        int trow = (r / 36864) * 96 + (r - arow * 96);  // b*96 + n
        int j = q * 4;
        f32x4 av = *(const f32x4*)(g_A + arow * 640 + j);
        f32x4 tv = *(const f32x4*)(g_T + trow * 640 + j);
        float h0 = fast_tanh(av[0] + tv[0]);
        float h1 = fast_tanh(av[1] + tv[1]);
        float h2 = fast_tanh(av[2] + tv[2]);
        float h3 = fast_tanh(av[3] + tv[3]);
        unsigned lo = (unsigned)f2bf(h0) | ((unsigned)f2bf(h1) << 16);
        unsigned hi = (unsigned)f2bf(h2) | ((unsigned)f2bf(h3) << 16);
        // group g = j/8 = q/2, swizzle g ^= (row&7); half-group select = q&1
        unsigned off = row * 1280 + (((unsigned)((q >> 1) ^ (row & 7))) << 4) + (q & 1) * 8;
        *(uint2*)(hb + off) = make_uint2(lo, hi);
    }
    __syncthreads();

    // ---- Phase 2: MFMA GEMM, no barriers in K-loop (compiler-scheduled) ----
    const int lane = tid & 63;
    const int wave = tid >> 6;     // 0..3
    const int l15  = lane & 15;
    const int quad = lane >> 4;    // 0..3

    for (int ct = 0; ct < 4; ++ct) {
        const int colw = ct * 256 + wave * 64;
        f32x4 acc[4][4] = {};
        for (int kb = 0; kb < 640; kb += 32) {
            const int g = (kb >> 3) + quad;       // 16B-group index along K
            short8 af[4], bf[4];
            #pragma unroll
            for (int mt = 0; mt < 4; ++mt) {
                int row = mt * 16 + l15;
                af[mt] = *(const short8*)(hb + row * 1280 + ((unsigned)(g ^ (row & 7)) << 4));
            }
            #pragma unroll
            for (int nt = 0; nt < 4; ++nt) {
                int col = colw + nt * 16 + l15;
                bf[nt] = *(const short8*)(g_W2 + ((size_t)g * 1024 + col) * 8);
            }
            // Swapped operands: D = (W2-frag as A) * (h-frag as B)
            //  -> lane l, reg rg holds out[row = mt*16 + (l&15)]
            //                             [col = colw + nt*16 + (l>>4)*4 + rg]
            #pragma unroll
            for (int mt = 0; mt < 4; ++mt)
                #pragma unroll
                for (int nt = 0; nt < 4; ++nt)
                    acc[mt][nt] = __builtin_amdgcn_mfma_f32_16x16x32_bf16(
                        bf[nt], af[mt], acc[mt][nt], 0, 0, 0);
        }
        // epilogue: add b_join, store fp32 as float4 (PLAIN cached stores).
        // mt-outer/nt-inner: both 64B halves of each 128B line are written by
        // adjacent instructions -> full-line dirty, no partial evictions.
        f32x4 bj[4];
        #pragma unroll
        for (int nt = 0; nt < 4; ++nt)
            bj[nt] = *(const f32x4*)(b_join + colw + nt * 16 + quad * 4);
        #pragma unroll
        for (int mt = 0; mt < 4; ++mt) {
            float* orow = out + (size_t)(r0 + mt * 16 + l15) * 1024;
            #pragma unroll
            for (int nt = 0; nt < 4; ++nt) {
                int c4 = colw + nt * 16 + quad * 4;
                f32x4 v = acc[mt][nt] + bj[nt];
                *(f32x4*)(orow + c4) = v;
            }
        }
    }
}

// ---------------------------------------------------------------------------
extern "C" void kernel_launch(void* const* d_in, const int* in_sizes, int n_in,
                              void* d_out, int out_size, void* d_ws, size_t ws_size,
                              hipStream_t stream) {
    const float* enc     = (const float*)d_in[0];
    const float* dec     = (const float*)d_in[1];
    const float* w_audio = (const float*)d_in[2];
    const float* b_audio = (const float*)d_in[3];
    const float* w_text  = (const float*)d_in[4];
    const float* b_text  = (const float*)d_in[5];
    const float* w_join  = (const float*)d_in[6];
    const float* b_join  = (const float*)d_in[7];
    float* out = (float*)d_out;

    pack_kernel<<<dim3(880), dim3(256), 0, stream>>>(enc, dec, w_audio, w_text, w_join);
    proj_kernel<<<dim3(30), dim3(256), 0, stream>>>(b_audio, b_text);
    join_kernel<<<dim3(1152), dim3(256), 0, stream>>>(b_join, out);
}

// Round 6
// 458.628 us; speedup vs baseline: 2.0145x; 1.0866x over previous
//
#include <hip/hip_runtime.h>
#include <hip/hip_bf16.h>

// Problem constants
// B=2, M=384, N=96, D=512, J=640, C=1024
// a = enc @ w_audio + b_audio : [768][640]   (proj_kernel, MFMA bf16-split)
// t = dec @ w_text  + b_text  : [192][640]
// out[r][c] = sum_j tanh(a[..][j] + t[..][j]) * w_join[j][c] + b_join[c]
//   r = (b*384+m)*96 + n  (73728 rows), c in [0,1024)

typedef float f32x4 __attribute__((ext_vector_type(4)));
typedef short short8 __attribute__((ext_vector_type(8)));

// Static device scratch — fully rewritten every launch (graph-replay safe).
__device__ float g_A[768 * 640];
__device__ float g_T[192 * 640];
__device__ short g_W2[80 * 1024 * 8];        // w_join bf16, [g][c][8k]
__device__ short g_Xph[960 * 512];           // enc(768)+dec(192) bf16 hi, fragment layout
__device__ short g_Xpl[960 * 512];           // residual lo
__device__ short g_Wph[2 * 64 * 640 * 8];    // w_audio/w_text bf16 hi, [mat][g][j][8k]
__device__ short g_Wpl[2 * 64 * 640 * 8];    // residual lo

__device__ __forceinline__ unsigned short f2bf(float f) {
    unsigned u = __float_as_uint(f);
    unsigned r = u + 0x7fffu + ((u >> 16) & 1u);   // RNE
    return (unsigned short)(r >> 16);
}
__device__ __forceinline__ float bf2f(unsigned short h) {
    return __uint_as_float((unsigned)h << 16);
}
__device__ __forceinline__ float fast_tanh(float x) {
    x = fminf(fmaxf(x, -10.f), 10.f);
    float e2 = __expf(x * 2.0f);
    return 1.f - 2.f / (e2 + 1.f);
}

// ---------------------------------------------------------------------------
// Pack kernel: 880 blocks x 256 = 225280 threads.
//   [0, 61440)        : X = enc|dec -> bf16 hi/lo fragments [row/16][g][row%16][8]
//   [61440, 143360)   : W = w_audio|w_text -> hi/lo [mat*64+g][j][8]  (k-group layout)
//   [143360, 225280)  : w_join -> g_W2 [g][c][8]  (bf16, single)
// ---------------------------------------------------------------------------
__global__ __launch_bounds__(256) void pack_kernel(
    const float* __restrict__ enc, const float* __restrict__ dec,
    const float* __restrict__ w_audio, const float* __restrict__ w_text,
    const float* __restrict__ w_join)
{
    int idx = blockIdx.x * 256 + threadIdx.x;
    if (idx < 61440) {
        int row = idx >> 6, g = idx & 63;
        const float* src = (row < 768) ? (enc + (size_t)row * 512)
                                       : (dec + (size_t)(row - 768) * 512);
        short8 hi, lo;
        #pragma unroll
        for (int i = 0; i < 8; ++i) {
            float x = src[g * 8 + i];
            unsigned short h = f2bf(x);
            hi[i] = (short)h;
            lo[i] = (short)f2bf(x - bf2f(h));
        }
        size_t off = ((size_t)(row >> 4) * 64 + g) * 16 + (row & 15);
        ((short8*)g_Xph)[off] = hi;
        ((short8*)g_Xpl)[off] = lo;
    } else if (idx < 143360) {
        int e = idx - 61440;
        int mat = e / 40960; e -= mat * 40960;
        int g = e / 640, j = e - g * 640;
        const float* W = mat ? w_text : w_audio;
        short8 hi, lo;
        #pragma unroll
        for (int i = 0; i < 8; ++i) {
            float x = W[(size_t)(g * 8 + i) * 640 + j];
            unsigned short h = f2bf(x);
            hi[i] = (short)h;
            lo[i] = (short)f2bf(x - bf2f(h));
        }
        size_t off = (size_t)(mat * 64 + g) * 640 + j;
        ((short8*)g_Wph)[off] = hi;
        ((short8*)g_Wpl)[off] = lo;
    } else {
        int e = idx - 143360;                 // 0..81919
        int g = e >> 10, c = e & 1023;
        short8 v;
        #pragma unroll
        for (int j = 0; j < 8; ++j)
            v[j] = (short)f2bf(w_join[(size_t)(g * 8 + j) * 1024 + c]);
        ((short8*)g_W2)[e] = v;
    }
}

// ---------------------------------------------------------------------------
// Projection GEMM via MFMA bf16 hi/lo split (fp32-equivalent accuracy):
//   x*w ~= xh*wh + xl*wh + xh*wl   (lo*lo ~ 2^-18, dropped)
// 30 blocks (15 M-tiles x 2 col-halves) x 256 threads; all operands from L2.
// Output: g_A rows 0..767 (enc@w_audio+b_audio), g_T rows 0..191.
// ---------------------------------------------------------------------------
__global__ __launch_bounds__(256) void proj_kernel(
    const float* __restrict__ b_audio, const float* __restrict__ b_text)
{
    const int bid = blockIdx.x;            // 0..29
    const int mtile = bid >> 1, nhalf = bid & 1;
    const int tid  = threadIdx.x;
    const int lane = tid & 63, wave = tid >> 6, l15 = lane & 15, quad = lane >> 4;
    const int mat  = (mtile >= 12) ? 1 : 0;       // 12*64 = 768 = enc rows
    const int colw = nhalf * 320 + wave * 80;     // 5 nt-tiles of 16
    const float* bias = mat ? b_text : b_audio;
    float* O = mat ? g_T : g_A;
    const int orow0 = mtile * 64 - mat * 768;

    const short8* Xh = (const short8*)g_Xph;
    const short8* Xl = (const short8*)g_Xpl;
    const short8* Wh = (const short8*)g_Wph;
    const short8* Wl = (const short8*)g_Wpl;

    f32x4 acc[4][5] = {};
    for (int kb = 0; kb < 512; kb += 32) {
        const int g = (kb >> 3) + quad;           // k-group 0..63
        short8 ah[4], al[4], bh[5], bl[5];
        #pragma unroll
        for (int mt = 0; mt < 4; ++mt) {
            size_t xo = ((size_t)(mtile * 4 + mt) * 64 + g) * 16 + l15;
            ah[mt] = Xh[xo]; al[mt] = Xl[xo];
        }
        #pragma unroll
        for (int nt = 0; nt < 5; ++nt) {
            size_t wo = (size_t)(mat * 64 + g) * 640 + colw + nt * 16 + l15;
            bh[nt] = Wh[wo]; bl[nt] = Wl[wo];
        }
        #pragma unroll
        for (int mt = 0; mt < 4; ++mt)
            #pragma unroll
            for (int nt = 0; nt < 5; ++nt) {
                acc[mt][nt] = __builtin_amdgcn_mfma_f32_16x16x32_bf16(bh[nt], ah[mt], acc[mt][nt], 0, 0, 0);
                acc[mt][nt] = __builtin_amdgcn_mfma_f32_16x16x32_bf16(bh[nt], al[mt], acc[mt][nt], 0, 0, 0);
                acc[mt][nt] = __builtin_amdgcn_mfma_f32_16x16x32_bf16(bl[nt], ah[mt], acc[mt][nt], 0, 0, 0);
            }
    }
    // lane l, reg rg -> out[row = mt*16 + (l&15)][col = colw + nt*16 + (l>>4)*4 + rg]
    #pragma unroll
    for (int nt = 0; nt < 5; ++nt) {
        const int c4 = colw + nt * 16 + quad * 4;
        f32x4 bj = *(const f32x4*)(bias + c4);
        #pragma unroll
        for (int mt = 0; mt < 4; ++mt) {
            f32x4 v = acc[mt][nt] + bj;
            *(f32x4*)(O + (size_t)(orow0 + mt * 16 + l15) * 640 + c4) = v;
        }
    }
}

// ---------------------------------------------------------------------------
// Main fused join kernel: 1152 blocks x 512 threads (8 waves).
// v6: v5's memory behavior (64-row tile, 80KiB LDS, 2 blocks/CU, PLAIN
//     cached stores, compiler-scheduled K-loop, no setprio) but 2x the
//     waves: 512 threads -> 16 waves/CU (4/SIMD) for latency hiding.
//     Wave tile = 64 rows x 32 cols per ct-iter (acc[4][2], ~95 VGPR,
//     fits the (512,4) 128-VGPR cap). Plain stores combine partial 128B
//     lines in L2 (robust to stream concurrency — v3's RFO blow-up was
//     NT-store-specific).
// ---------------------------------------------------------------------------
__global__ __launch_bounds__(512, 4) void join_kernel(
    const float* __restrict__ b_join, // [1024]
    float* __restrict__ out)          // [73728][1024]
{
    __shared__ char hb[64 * 1280];    // 80 KiB: row stride 1280B, 16B groups XOR-swizzled
    const int tid = threadIdx.x;
    const int r0  = blockIdx.x * 64;

    // ---- Phase 1: h = tanh(a + t) -> LDS (bf16), once per element ----
    for (int e = tid; e < 64 * 160; e += 512) {
        int row = e / 160;
        int q   = e - row * 160;       // float4 index within row, j = 4q
        int r   = r0 + row;
        int arow = r / 96;                              // b*384 + m
        int trow = (r / 36864) * 96 + (r - arow * 96);  // b*96 + n
        int j = q * 4;
        f32x4 av = *(const f32x4*)(g_A + arow * 640 + j);
        f32x4 tv = *(const f32x4*)(g_T + trow * 640 + j);
        float h0 = fast_tanh(av[0] + tv[0]);
        float h1 = fast_tanh(av[1] + tv[1]);
        float h2 = fast_tanh(av[2] + tv[2]);
        float h3 = fast_tanh(av[3] + tv[3]);
        unsigned lo = (unsigned)f2bf(h0) | ((unsigned)f2bf(h1) << 16);
        unsigned hi = (unsigned)f2bf(h2) | ((unsigned)f2bf(h3) << 16);
        // group g = j/8 = q/2, swizzle g ^= (row&7); half-group select = q&1
        unsigned off = row * 1280 + (((unsigned)((q >> 1) ^ (row & 7))) << 4) + (q & 1) * 8;
        *(uint2*)(hb + off) = make_uint2(lo, hi);
    }
    __syncthreads();

    // ---- Phase 2: MFMA GEMM, no barriers in K-loop (compiler-scheduled) ----
    const int lane = tid & 63;
    const int wave = tid >> 6;     // 0..7
    const int l15  = lane & 15;
    const int quad = lane >> 4;    // 0..3

    for (int ct = 0; ct < 4; ++ct) {
        const int colw = ct * 256 + wave * 32;
        f32x4 acc[4][2] = {};
        for (int kb = 0; kb < 640; kb += 32) {
            const int g = (kb >> 3) + quad;       // 16B-group index along K
            short8 af[4], bf[2];
            #pragma unroll
            for (int mt = 0; mt < 4; ++mt) {
                int row = mt * 16 + l15;
                af[mt] = *(const short8*)(hb + row * 1280 + ((unsigned)(g ^ (row & 7)) << 4));
            }
            #pragma unroll
            for (int nt = 0; nt < 2; ++nt) {
                int col = colw + nt * 16 + l15;
                bf[nt] = *(const short8*)(g_W2 + ((size_t)g * 1024 + col) * 8);
            }
            // Swapped operands: D = (W2-frag as A) * (h-frag as B)
            //  -> lane l, reg rg holds out[row = mt*16 + (l&15)]
            //                             [col = colw + nt*16 + (l>>4)*4 + rg]
            #pragma unroll
            for (int mt = 0; mt < 4; ++mt)
                #pragma unroll
                for (int nt = 0; nt < 2; ++nt)
                    acc[mt][nt] = __builtin_amdgcn_mfma_f32_16x16x32_bf16(
                        bf[nt], af[mt], acc[mt][nt], 0, 0, 0);
        }
        // epilogue: add b_join, store fp32 as float4 (PLAIN cached stores).
        // nt=0/1 adjacent: both 64B halves of each 128B line written
        // back-to-back -> full-line dirty in L2, no read-allocate.
        f32x4 bj[2];
        #pragma unroll
        for (int nt = 0; nt < 2; ++nt)
            bj[nt] = *(const f32x4*)(b_join + colw + nt * 16 + quad * 4);
        #pragma unroll
        for (int mt = 0; mt < 4; ++mt) {
            float* orow = out + (size_t)(r0 + mt * 16 + l15) * 1024;
            #pragma unroll
            for (int nt = 0; nt < 2; ++nt) {
                int c4 = colw + nt * 16 + quad * 4;
                f32x4 v = acc[mt][nt] + bj[nt];
                *(f32x4*)(orow + c4) = v;
            }
        }
    }
}

// ---------------------------------------------------------------------------
extern "C" void kernel_launch(void* const* d_in, const int* in_sizes, int n_in,
                              void* d_out, int out_size, void* d_ws, size_t ws_size,
                              hipStream_t stream) {
    const float* enc     = (const float*)d_in[0];
    const float* dec     = (const float*)d_in[1];
    const float* w_audio = (const float*)d_in[2];
    const float* b_audio = (const float*)d_in[3];
    const float* w_text  = (const float*)d_in[4];
    const float* b_text  = (const float*)d_in[5];
    const float* w_join  = (const float*)d_in[6];
    const float* b_join  = (const float*)d_in[7];
    float* out = (float*)d_out;

    pack_kernel<<<dim3(880), dim3(256), 0, stream>>>(enc, dec, w_audio, w_text, w_join);
    proj_kernel<<<dim3(30), dim3(256), 0, stream>>>(b_audio, b_text);
    join_kernel<<<dim3(1152), dim3(512), 0, stream>>>(b_join, out);
}